// Round 10
// baseline (3781.722 us; speedup 1.0000x reference)
//
#include <hip/hip_runtime.h>

#define BATCH   4
#define NPTS    8192
#define NPOINT  2048
#define NSAMPLE 32
#define NCH     67
#define NOUT    128
#define FPS_T   512
#define NWAVE   (FPS_T / 64)     // 8 waves (2 per SIMD)
#define KPT     (NPTS / FPS_T)   // 16 points per thread (setup passes)
#define NBKT    64               // 4x4x4 spatial buckets, bucket == lane
#define NFPS    4                // fps blocks (one per batch)
#define NBLK    40               // 4 fps + 36 workers (worker work ~6us/ticket
                                 // x ~28 tickets each << fps duration; fewer
                                 // spinners => less LLC contention)
#define TPT     8                // centers per worker ticket
#define NTICK   (BATCH * NPOINT / TPT)   // 1024 tickets
#define SENT    0xFFFFFFFFu      // NaN bit pattern from memset 0xFF

// DPP ctrl encodings (gfx9/CDNA)
#define DPP_ROW_SHR1    0x111
#define DPP_ROW_SHR2    0x112
#define DPP_ROW_SHR4    0x114
#define DPP_ROW_SHR8    0x118
#define DPP_ROW_BCAST15 0x142
#define DPP_ROW_BCAST31 0x143

// one u32 max DPP hop (pattern-matches to v_max_u32 with DPP operand);
// bound_ctrl=1 zero-fills edge lanes; 0 is the max identity.
#define DPP_U32MAX_HOP(v, ctrl)                                                \
    {                                                                          \
        unsigned _o = (unsigned)__builtin_amdgcn_update_dpp(                   \
            0, (int)(v), (ctrl), 0xF, 0xF, true);                              \
        (v) = (_o > (v)) ? _o : (v);                                           \
    }

// full-wave u32 max reduce, result in lane 63
#define DPP_REDUCE_MAX_U32(v)            \
    DPP_U32MAX_HOP(v, DPP_ROW_SHR1);     \
    DPP_U32MAX_HOP(v, DPP_ROW_SHR2);     \
    DPP_U32MAX_HOP(v, DPP_ROW_SHR4);     \
    DPP_U32MAX_HOP(v, DPP_ROW_SHR8);     \
    DPP_U32MAX_HOP(v, DPP_ROW_BCAST15);  \
    DPP_U32MAX_HOP(v, DPP_ROW_BCAST31);

// ---------------------------------------------------------------------------
// Fused kernel, fence-free handoff (R9 scheme). Blocks 0-3: bucketed FPS
// (bit-exact R7 math; argmax now via hi/lo-split u32-max DPP reduce: 6 hops
// on dist bits, readlane-broadcast, mask, 6 hops on payload — identical
// semantics to the u64 compare, ~half the instructions). Blocks 4-39:
// workers (ticket -> data-as-flag spin on sentinel -> per-wave ball query ->
// gather -> conv). new_xyz pre-set to 0xFF; publishes are RELAXED agent-
// scope dword stores batched 16 centers at a time through an LDS ring.
// ---------------------------------------------------------------------------
__global__ __launch_bounds__(FPS_T) void fused_kernel(
    const float* __restrict__ points, const float* __restrict__ features,
    const float* __restrict__ weight, float* __restrict__ new_xyz,
    float* __restrict__ conv_out, int* __restrict__ ctl)
{
    __shared__ __attribute__((aligned(16))) char smem[149504];
    const int t    = threadIdx.x;
    const int lane = t & 63;
    const int w    = t >> 6;
    int* ticket = ctl;          // zeroed by hipMemsetAsync

    if (blockIdx.x < NFPS) {
        // =================== FPS path ======================================
#pragma clang fp contract(off)
        const int b = blockIdx.x;
        const float* pts = points + (size_t)b * NPTS * 3;
        int* nxz_i = (int*)(new_xyz + (size_t)b * NPOINT * 3);

        float2* xy = (float2*)smem;                               // 65536
        float2* zd = (float2*)(smem + 65536);                     // 65536
        unsigned short* orig16 = (unsigned short*)(smem + 131072);// 16384
        unsigned long long (*key_g)[NBKT] =
            (unsigned long long (*)[NBKT])(smem + 147456);        // 1024
        int* start  = (int*)(smem + 148480);                      // 260
        int* cursor = (int*)(smem + 148744);                      // 256
        float (*bbr)[NWAVE] = (float (*)[NWAVE])(smem + 149000);  // 192
        float* cbuf = (float*)(smem + 149192);                    // 192 (ring)

        // setup: bbox
        float mnx = 1e30f, mny = 1e30f, mnz = 1e30f;
        float mxx = -1e30f, mxy = -1e30f, mxz = -1e30f;
        for (int k = 0; k < KPT; ++k) {
            const int i = k * FPS_T + t;
            float xx = pts[3 * i], yy = pts[3 * i + 1], zz = pts[3 * i + 2];
            mnx = fminf(mnx, xx); mxx = fmaxf(mxx, xx);
            mny = fminf(mny, yy); mxy = fmaxf(mxy, yy);
            mnz = fminf(mnz, zz); mxz = fmaxf(mxz, zz);
        }
#pragma unroll
        for (int off = 32; off >= 1; off >>= 1) {
            mnx = fminf(mnx, __shfl_down(mnx, off));
            mny = fminf(mny, __shfl_down(mny, off));
            mnz = fminf(mnz, __shfl_down(mnz, off));
            mxx = fmaxf(mxx, __shfl_down(mxx, off));
            mxy = fmaxf(mxy, __shfl_down(mxy, off));
            mxz = fmaxf(mxz, __shfl_down(mxz, off));
        }
        if (lane == 0) {
            bbr[0][w] = mnx; bbr[1][w] = mny; bbr[2][w] = mnz;
            bbr[3][w] = mxx; bbr[4][w] = mxy; bbr[5][w] = mxz;
        }
        if (t < NBKT) cursor[t] = 0;
        __syncthreads();
        mnx = bbr[0][0]; mny = bbr[1][0]; mnz = bbr[2][0];
        mxx = bbr[3][0]; mxy = bbr[4][0]; mxz = bbr[5][0];
#pragma unroll
        for (int q = 1; q < NWAVE; ++q) {
            mnx = fminf(mnx, bbr[0][q]); mny = fminf(mny, bbr[1][q]);
            mnz = fminf(mnz, bbr[2][q]); mxx = fmaxf(mxx, bbr[3][q]);
            mxy = fmaxf(mxy, bbr[4][q]); mxz = fmaxf(mxz, bbr[5][q]);
        }
        const float rx = mxx - mnx, ry = mxy - mny, rz = mxz - mnz;
        const float sclx = (rx > 0.f) ? 4.0f / rx : 0.f;
        const float scly = (ry > 0.f) ? 4.0f / ry : 0.f;
        const float sclz = (rz > 0.f) ? 4.0f / rz : 0.f;

        // setup: histogram
        for (int k = 0; k < KPT; ++k) {
            const int i = k * FPS_T + t;
            float xx = pts[3 * i], yy = pts[3 * i + 1], zz = pts[3 * i + 2];
            int cxi = min(3, max(0, (int)((xx - mnx) * sclx)));
            int cyi = min(3, max(0, (int)((yy - mny) * scly)));
            int czi = min(3, max(0, (int)((zz - mnz) * sclz)));
            atomicAdd(&cursor[cxi | (cyi << 2) | (czi << 4)], 1);
        }
        __syncthreads();
        if (t == 0) {
            int acc = 0;
            for (int g = 0; g < NBKT; ++g) { start[g] = acc; acc += cursor[g]; }
            start[NBKT] = acc;
        }
        __syncthreads();
        const int vs0 = start[lane];
        const int vln = start[lane + 1] - vs0;
        if (t < NBKT) cursor[t] = start[t];
        __syncthreads();

        // setup: scatter (counting sort)
        for (int k = 0; k < KPT; ++k) {
            const int i = k * FPS_T + t;
            float xx = pts[3 * i], yy = pts[3 * i + 1], zz = pts[3 * i + 2];
            int cxi = min(3, max(0, (int)((xx - mnx) * sclx)));
            int cyi = min(3, max(0, (int)((yy - mny) * scly)));
            int czi = min(3, max(0, (int)((zz - mnz) * sclz)));
            int slot = atomicAdd(&cursor[cxi | (cyi << 2) | (czi << 4)], 1);
            xy[slot] = make_float2(xx, yy);
            zd[slot] = make_float2(zz, 10000000000.0f);
            orig16[slot] = (unsigned short)i;
        }

        const float cwx = rx * 0.25f, cwy = ry * 0.25f, cwz = rz * 0.25f;
        const float bxl = mnx + (float)(lane & 3) * cwx,        bxh = bxl + cwx;
        const float byl = mny + (float)((lane >> 2) & 3) * cwy, byh = byl + cwy;
        const float bzl = mnz + (float)((lane >> 4) & 3) * cwz, bzh = bzl + cwz;
        const unsigned long long below = (1ull << lane) - 1ull;

        float cx = pts[0], cy = pts[1], cz = pts[2];
        if (t == 0) { cbuf[0] = cx; cbuf[1] = cy; cbuf[2] = cz; }  // ring slot 0
        unsigned long long kk =
            ((unsigned long long)__float_as_uint(10000000000.0f) << 32);
        __syncthreads();

        for (int it = 1; it < NPOINT; ++it) {
            const int par = it & 1;
            float ddx = fmaxf(fmaxf(bxl - cx, cx - bxh), 0.0f);
            float ddy = fmaxf(fmaxf(byl - cy, cy - byh), 0.0f);
            float ddz = fmaxf(fmaxf(bzl - cz, cz - bzh), 0.0f);
            float dmin2 = ddx * ddx + ddy * ddy + ddz * ddz;
            float ub = __uint_as_float((unsigned)(kk >> 32));
            bool scan = dmin2 < ub * 1.0001f + 1e-5f;
            unsigned long long m = __ballot(scan);

            const int rank = (int)__popcll(m & below);
            const bool mine = scan && ((rank & (NWAVE - 1)) == w);
            unsigned long long mw = __ballot(mine);

            while (mw) {
                const int g = __ffsll((long long)mw) - 1;
                mw &= mw - 1;
                const int s0 = __builtin_amdgcn_readlane(vs0, g);
                const int ln = __builtin_amdgcn_readlane(vln, g);
                unsigned long long bk = 0;
                for (int jo = lane; jo < ln; jo += 64) {
                    const int j = s0 + jo;
                    float2 vxy = xy[j];
                    float2 vzd = zd[j];
                    float dx = vxy.x - cx;
                    float dy = vxy.y - cy;
                    float dz = vzd.x - cz;
                    float d  = ((dx * dx) + (dy * dy)) + (dz * dz);
                    float nd = fminf(vzd.y, d);
                    zd[j].y = nd;
                    unsigned long long kkey =
                        ((unsigned long long)__float_as_uint(nd) << 32)
                      | ((unsigned)(8191 - (int)orig16[j]) << 13)
                      | (unsigned)j;
                    if (kkey > bk) bk = kkey;
                }
                // hi/lo split wave argmax: 6 u32-max hops on dist word,
                // broadcast, mask, 6 hops on payload. Ties in dist resolve
                // by max payload = min original index (same as u64 compare).
                const unsigned bhi0 = (unsigned)(bk >> 32);
                unsigned hmax = bhi0;
                DPP_REDUCE_MAX_U32(hmax);
                hmax = (unsigned)__builtin_amdgcn_readlane((int)hmax, 63);
                unsigned lo2 = (bhi0 == hmax) ? (unsigned)bk : 0u;
                DPP_REDUCE_MAX_U32(lo2);
                if (lane == 63)
                    key_g[par][g] = ((unsigned long long)hmax << 32) | lo2;
            }
            __syncthreads();

            if (scan) kk = key_g[par][lane];
            const unsigned khi = (unsigned)(kk >> 32);
            unsigned hmax = khi;
            DPP_REDUCE_MAX_U32(hmax);
            hmax = (unsigned)__builtin_amdgcn_readlane((int)hmax, 63);
            unsigned lo2 = (khi == hmax) ? (unsigned)kk : 0u;
            DPP_REDUCE_MAX_U32(lo2);
            const unsigned rlo =
                (unsigned)__builtin_amdgcn_readlane((int)lo2, 63);
            const int slot = (int)(rlo & 0x1FFFu);
            float2 wxy = xy[slot];
            float2 wzd = zd[slot];
            cx = wxy.x; cy = wxy.y; cz = wzd.x;
            // bank the center into the LDS ring (slot = it mod 16)
            if (t == 0) {
                const int rs = (it & 15) * 3;
                cbuf[rs] = cx; cbuf[rs + 1] = cy; cbuf[rs + 2] = cz;
            }
            // every 16 iters: lanes 0-47 of wave 0 flush 16 centers with
            // relaxed agent-scope stores — no fence, no L2 writeback.
            if (((it & 15) == 15) && t < 48) {
                const int base3 = (it & ~15) * 3;
                __hip_atomic_store(&nxz_i[base3 + t],
                                   __float_as_int(cbuf[t]),
                                   __ATOMIC_RELAXED, __HIP_MEMORY_SCOPE_AGENT);
            }
        }
        return;
    }

    // ======================= worker path ===================================
    float (*g)[NCH][NSAMPLE] = (float (*)[NCH][NSAMPLE])smem;  // 68608 B
    int (*idx)[NSAMPLE] = (int (*)[NSAMPLE])(smem + 68608);    //  1024 B
    float (*cc)[4] = (float (*)[4])(smem + 69632);             //   128 B
    int* tk_s = (int*)(smem + 69760);

    const int* nxz_all = (const int*)new_xyz;

    for (;;) {
        if (t == 0) *tk_s = atomicAdd(ticket, 1);
        __syncthreads();
        const int T = *tk_s;
        __syncthreads();
        if (T >= NTICK) break;
        const int b   = T & 3;
        const int it0 = (T >> 2) * TPT;

        const float* pts = points + (size_t)b * NPTS * 3;
        const float* fts = features + (size_t)b * NPTS * 64;
        const int gci = b * NPOINT + it0 + w;   // this wave's center

        // ---- spin until this center's 3 coords are published (data=flag) --
        float cxw = 0.f, cyw = 0.f, czw = 0.f;
        if (lane == 0) {
            unsigned v;
            do {
                v = (unsigned)__hip_atomic_load(&nxz_all[3 * gci + 0],
                        __ATOMIC_RELAXED, __HIP_MEMORY_SCOPE_AGENT);
                if (v != SENT) break;
                __builtin_amdgcn_s_sleep(8);
            } while (true);
            cxw = __uint_as_float(v);
            do {
                v = (unsigned)__hip_atomic_load(&nxz_all[3 * gci + 1],
                        __ATOMIC_RELAXED, __HIP_MEMORY_SCOPE_AGENT);
                if (v != SENT) break;
                __builtin_amdgcn_s_sleep(2);
            } while (true);
            cyw = __uint_as_float(v);
            do {
                v = (unsigned)__hip_atomic_load(&nxz_all[3 * gci + 2],
                        __ATOMIC_RELAXED, __HIP_MEMORY_SCOPE_AGENT);
                if (v != SENT) break;
                __builtin_amdgcn_s_sleep(2);
            } while (true);
            czw = __uint_as_float(v);
        }
        cxw = __shfl(cxw, 0); cyw = __shfl(cyw, 0); czw = __shfl(czw, 0);
        if (lane == 0) { cc[w][0] = cxw; cc[w][1] = cyw; cc[w][2] = czw; }

        // ---- ball query: wave w handles center it0+w (bit-exact) ----------
        {
#pragma clang fp contract(off)
            const float r2 = (float)(0.2 * 0.2);
            int* out = idx[w];
            int cnt = 0, first = 0;
            bool havefirst = false;
            for (int base = 0; base < NPTS && cnt < NSAMPLE; base += 64) {
                const int j = base + lane;
                float dx = pts[3 * j + 0] - cxw;
                float dy = pts[3 * j + 1] - cyw;
                float dz = pts[3 * j + 2] - czw;
                float d2 = ((dx * dx) + (dy * dy)) + (dz * dz);
                const bool in = d2 < r2;
                unsigned long long m = __ballot(in);
                if (in) {
                    int pos = cnt + __popcll(m & ((1ull << lane) - 1ull));
                    if (pos < NSAMPLE) out[pos] = j;
                }
                if (!havefirst && m != 0ull) {
                    first = base + (__ffsll((long long)m) - 1);
                    havefirst = true;
                }
                cnt += __popcll(m);
            }
            if (lane >= cnt && lane < NSAMPLE) out[lane] = first;
        }
        __syncthreads();

        // ---- gather: 256 slots, slot = p*32+s ----
        if (t < TPT * NSAMPLE) {
            const int p = t >> 5;
            const int s = t & 31;
            const int j = idx[p][s];
            const float* pj = pts + 3 * j;
            g[p][0][s] = pj[0] - cc[p][0];
            g[p][1][s] = pj[1] - cc[p][1];
            g[p][2][s] = pj[2] - cc[p][2];
            const float4* fj = (const float4*)(fts + (size_t)j * 64);
#pragma unroll
            for (int c4 = 0; c4 < 16; ++c4) {
                float4 v = fj[c4];
                g[p][3 + 4 * c4 + 0][s] = v.x;
                g[p][3 + 4 * c4 + 1][s] = v.y;
                g[p][3 + 4 * c4 + 2][s] = v.z;
                g[p][3 + 4 * c4 + 3][s] = v.w;
            }
        }
        __syncthreads();

        // ---- conv: o = t&127, quad q = t>>7 handles centers q and q+4 ----
        {
            const int o = t & 127;
            const int q = t >> 7;
            float acc0 = 0.f, acc1 = 0.f;
            const float* wr = weight + (size_t)o * NCH * NSAMPLE;
            for (int c = 0; c < NCH; ++c) {
                const float4* w4 = (const float4*)(wr + c * NSAMPLE);
#pragma unroll
                for (int s4 = 0; s4 < 8; ++s4) {
                    float4 wv = w4[s4];
                    float4 g0 = *(const float4*)&g[q][c][s4 * 4];
                    float4 g1 = *(const float4*)&g[q + 4][c][s4 * 4];
                    acc0 += g0.x * wv.x + g0.y * wv.y + g0.z * wv.z + g0.w * wv.w;
                    acc1 += g1.x * wv.x + g1.y * wv.y + g1.z * wv.z + g1.w * wv.w;
                }
            }
            float* outp = conv_out + ((size_t)b * NPOINT + it0) * NOUT;
            outp[(q    ) * NOUT + o] = acc0;
            outp[(q + 4) * NOUT + o] = acc1;
        }
        __syncthreads();   // protect g/idx/cc before next ticket's writes
    }
}

extern "C" void kernel_launch(void* const* d_in, const int* in_sizes, int n_in,
                              void* d_out, int out_size, void* d_ws, size_t ws_size,
                              hipStream_t stream)
{
    const float* points   = (const float*)d_in[0];
    const float* features = (const float*)d_in[1];
    const float* weight   = (const float*)d_in[2];

    float* new_xyz = (float*)d_out;                              // (4,2048,3)
    float* conv    = (float*)d_out + (size_t)BATCH * NPOINT * 3; // (4,2048,128)
    int* ctl = (int*)d_ws;   // ticket counter

    hipMemsetAsync(d_ws, 0, 64, stream);
    // seed new_xyz with 0xFFFFFFFF sentinel (NaN bits): data doubles as flag
    hipMemsetAsync(new_xyz, 0xFF, (size_t)BATCH * NPOINT * 3 * 4, stream);
    fused_kernel<<<NBLK, FPS_T, 0, stream>>>(points, features, weight,
                                             new_xyz, conv, ctl);
}

// Round 12
// 1855.795 us; speedup vs baseline: 2.0378x; 2.0378x over previous
//
#include <hip/hip_runtime.h>

#define BATCH   4
#define NPTS    8192
#define NPOINT  2048
#define NSAMPLE 32
#define NCH     67
#define NOUT    128
#define FPS_T   512
#define NWAVE   (FPS_T / 64)     // 8 waves (2 per SIMD)
#define KPT     (NPTS / FPS_T)   // 16 points per thread (setup passes)
#define NBKT    64               // 4x4x4 spatial buckets, bucket == lane
#define NFPS    4                // fps blocks (one per batch)
#define NBLK    208              // 4 fps + 204 workers (~45us/ticket => 4.5x
                                 // headroom over ~0.62 tickets/us production)
#define TPT     8                // centers per worker ticket
#define NTICK   (BATCH * NPOINT / TPT)   // 1024 tickets
#define SENT    0xFFFFFFFFu      // NaN bit pattern from memset 0xFF
#define PUB     16               // publish period; 3*PUB=48 <= 64 so the
                                 // flush stays inside wave 0 (same-wave DS
                                 // ordering makes the t0 ring write visible
                                 // without a barrier — PUB=32 raced, R11)

// DPP ctrl encodings (gfx9/CDNA)
#define DPP_ROW_SHR1    0x111
#define DPP_ROW_SHR2    0x112
#define DPP_ROW_SHR4    0x114
#define DPP_ROW_SHR8    0x118
#define DPP_ROW_BCAST15 0x142
#define DPP_ROW_BCAST31 0x143

// max-combine one DPP hop on a packed u64 key (R7/R9 known-good form).
#define DPP_MAX_HOP(key, ctrl)                                                 \
    {                                                                          \
        int _lo = (int)(unsigned)(key);                                        \
        int _hi = (int)(unsigned)((key) >> 32);                                \
        int _olo = __builtin_amdgcn_update_dpp(0, _lo, (ctrl), 0xF, 0xF, true);\
        int _ohi = __builtin_amdgcn_update_dpp(0, _hi, (ctrl), 0xF, 0xF, true);\
        unsigned long long _o =                                                \
            ((unsigned long long)(unsigned)_ohi << 32) | (unsigned)_olo;       \
        if (_o > (key)) (key) = _o;                                            \
    }

#define DPP_REDUCE_MAX(key)            \
    DPP_MAX_HOP(key, DPP_ROW_SHR1);    \
    DPP_MAX_HOP(key, DPP_ROW_SHR2);    \
    DPP_MAX_HOP(key, DPP_ROW_SHR4);    \
    DPP_MAX_HOP(key, DPP_ROW_SHR8);    \
    DPP_MAX_HOP(key, DPP_ROW_BCAST15); \
    DPP_MAX_HOP(key, DPP_ROW_BCAST31);

// ---------------------------------------------------------------------------
// Fused kernel. Blocks 0-3: bucketed FPS (bit-exact R7 math, u64 DPP argmax)
// + relaxed agent-scope publish every PUB iters via a wave-0 LDS ring, then
// one relaxed prog[b] store. Blocks 4-207: workers: ticket -> block-level
// poll of prog[b] (one hot LLC line, s_sleep) -> per-center sentinel
// backstop (correct under any store-visibility order) -> per-wave ball query
// -> gather -> conv. 208 blocks, 1 block/CU => all co-resident, fps never
// waits on workers => deadlock-free.
// ---------------------------------------------------------------------------
__global__ __launch_bounds__(FPS_T) void fused_kernel(
    const float* __restrict__ points, const float* __restrict__ features,
    const float* __restrict__ weight, float* __restrict__ new_xyz,
    float* __restrict__ conv_out, int* __restrict__ ctl)
{
    __shared__ __attribute__((aligned(16))) char smem[149504];
    const int t    = threadIdx.x;
    const int lane = t & 63;
    const int w    = t >> 6;
    int* prog   = ctl;          // prog[0..3]
    int* ticket = ctl + 32;     // byte offset 128; all zeroed by memset

    if (blockIdx.x < NFPS) {
        // =================== FPS path ======================================
#pragma clang fp contract(off)
        const int b = blockIdx.x;
        const float* pts = points + (size_t)b * NPTS * 3;
        int* nxz_i = (int*)(new_xyz + (size_t)b * NPOINT * 3);

        float2* xy = (float2*)smem;                               // 65536
        float2* zd = (float2*)(smem + 65536);                     // 65536
        unsigned short* orig16 = (unsigned short*)(smem + 131072);// 16384
        unsigned long long (*key_g)[NBKT] =
            (unsigned long long (*)[NBKT])(smem + 147456);        // 1024
        int* start  = (int*)(smem + 148480);                      // 260
        int* cursor = (int*)(smem + 148744);                      // 256
        float (*bbr)[NWAVE] = (float (*)[NWAVE])(smem + 149000);  // 192
        float* cbuf = (float*)(smem + 149192);                    // 192 (ring)

        // setup: bbox
        float mnx = 1e30f, mny = 1e30f, mnz = 1e30f;
        float mxx = -1e30f, mxy = -1e30f, mxz = -1e30f;
        for (int k = 0; k < KPT; ++k) {
            const int i = k * FPS_T + t;
            float xx = pts[3 * i], yy = pts[3 * i + 1], zz = pts[3 * i + 2];
            mnx = fminf(mnx, xx); mxx = fmaxf(mxx, xx);
            mny = fminf(mny, yy); mxy = fmaxf(mxy, yy);
            mnz = fminf(mnz, zz); mxz = fmaxf(mxz, zz);
        }
#pragma unroll
        for (int off = 32; off >= 1; off >>= 1) {
            mnx = fminf(mnx, __shfl_down(mnx, off));
            mny = fminf(mny, __shfl_down(mny, off));
            mnz = fminf(mnz, __shfl_down(mnz, off));
            mxx = fmaxf(mxx, __shfl_down(mxx, off));
            mxy = fmaxf(mxy, __shfl_down(mxy, off));
            mxz = fmaxf(mxz, __shfl_down(mxz, off));
        }
        if (lane == 0) {
            bbr[0][w] = mnx; bbr[1][w] = mny; bbr[2][w] = mnz;
            bbr[3][w] = mxx; bbr[4][w] = mxy; bbr[5][w] = mxz;
        }
        if (t < NBKT) cursor[t] = 0;
        __syncthreads();
        mnx = bbr[0][0]; mny = bbr[1][0]; mnz = bbr[2][0];
        mxx = bbr[3][0]; mxy = bbr[4][0]; mxz = bbr[5][0];
#pragma unroll
        for (int q = 1; q < NWAVE; ++q) {
            mnx = fminf(mnx, bbr[0][q]); mny = fminf(mny, bbr[1][q]);
            mnz = fminf(mnz, bbr[2][q]); mxx = fmaxf(mxx, bbr[3][q]);
            mxy = fmaxf(mxy, bbr[4][q]); mxz = fmaxf(mxz, bbr[5][q]);
        }
        const float rx = mxx - mnx, ry = mxy - mny, rz = mxz - mnz;
        const float sclx = (rx > 0.f) ? 4.0f / rx : 0.f;
        const float scly = (ry > 0.f) ? 4.0f / ry : 0.f;
        const float sclz = (rz > 0.f) ? 4.0f / rz : 0.f;

        // setup: histogram
        for (int k = 0; k < KPT; ++k) {
            const int i = k * FPS_T + t;
            float xx = pts[3 * i], yy = pts[3 * i + 1], zz = pts[3 * i + 2];
            int cxi = min(3, max(0, (int)((xx - mnx) * sclx)));
            int cyi = min(3, max(0, (int)((yy - mny) * scly)));
            int czi = min(3, max(0, (int)((zz - mnz) * sclz)));
            atomicAdd(&cursor[cxi | (cyi << 2) | (czi << 4)], 1);
        }
        __syncthreads();
        if (t == 0) {
            int acc = 0;
            for (int g = 0; g < NBKT; ++g) { start[g] = acc; acc += cursor[g]; }
            start[NBKT] = acc;
        }
        __syncthreads();
        const int vs0 = start[lane];
        const int vln = start[lane + 1] - vs0;
        if (t < NBKT) cursor[t] = start[t];
        __syncthreads();

        // setup: scatter (counting sort)
        for (int k = 0; k < KPT; ++k) {
            const int i = k * FPS_T + t;
            float xx = pts[3 * i], yy = pts[3 * i + 1], zz = pts[3 * i + 2];
            int cxi = min(3, max(0, (int)((xx - mnx) * sclx)));
            int cyi = min(3, max(0, (int)((yy - mny) * scly)));
            int czi = min(3, max(0, (int)((zz - mnz) * sclz)));
            int slot = atomicAdd(&cursor[cxi | (cyi << 2) | (czi << 4)], 1);
            xy[slot] = make_float2(xx, yy);
            zd[slot] = make_float2(zz, 10000000000.0f);
            orig16[slot] = (unsigned short)i;
        }

        const float cwx = rx * 0.25f, cwy = ry * 0.25f, cwz = rz * 0.25f;
        const float bxl = mnx + (float)(lane & 3) * cwx,        bxh = bxl + cwx;
        const float byl = mny + (float)((lane >> 2) & 3) * cwy, byh = byl + cwy;
        const float bzl = mnz + (float)((lane >> 4) & 3) * cwz, bzh = bzl + cwz;
        const unsigned long long below = (1ull << lane) - 1ull;

        float cx = pts[0], cy = pts[1], cz = pts[2];
        if (t == 0) { cbuf[0] = cx; cbuf[1] = cy; cbuf[2] = cz; }  // ring slot 0
        unsigned long long kk =
            ((unsigned long long)__float_as_uint(10000000000.0f) << 32);
        __syncthreads();

        for (int it = 1; it < NPOINT; ++it) {
            const int par = it & 1;
            float ddx = fmaxf(fmaxf(bxl - cx, cx - bxh), 0.0f);
            float ddy = fmaxf(fmaxf(byl - cy, cy - byh), 0.0f);
            float ddz = fmaxf(fmaxf(bzl - cz, cz - bzh), 0.0f);
            float dmin2 = ddx * ddx + ddy * ddy + ddz * ddz;
            float ub = __uint_as_float((unsigned)(kk >> 32));
            bool scan = dmin2 < ub * 1.0001f + 1e-5f;
            unsigned long long m = __ballot(scan);

            const int rank = (int)__popcll(m & below);
            const bool mine = scan && ((rank & (NWAVE - 1)) == w);
            unsigned long long mw = __ballot(mine);

            while (mw) {
                const int g = __ffsll((long long)mw) - 1;
                mw &= mw - 1;
                const int s0 = __builtin_amdgcn_readlane(vs0, g);
                const int ln = __builtin_amdgcn_readlane(vln, g);
                unsigned long long bk = 0;
                for (int jo = lane; jo < ln; jo += 64) {
                    const int j = s0 + jo;
                    float2 vxy = xy[j];
                    float2 vzd = zd[j];
                    float dx = vxy.x - cx;
                    float dy = vxy.y - cy;
                    float dz = vzd.x - cz;
                    float d  = ((dx * dx) + (dy * dy)) + (dz * dz);
                    float nd = fminf(vzd.y, d);
                    zd[j].y = nd;
                    unsigned long long kkey =
                        ((unsigned long long)__float_as_uint(nd) << 32)
                      | ((unsigned)(8191 - (int)orig16[j]) << 13)
                      | (unsigned)j;
                    if (kkey > bk) bk = kkey;
                }
                DPP_REDUCE_MAX(bk);
                if (lane == 63) key_g[par][g] = bk;
            }
            __syncthreads();

            if (scan) kk = key_g[par][lane];
            unsigned long long rr = kk;
            DPP_REDUCE_MAX(rr);
            const unsigned rlo =
                (unsigned)__builtin_amdgcn_readlane((int)(unsigned)rr, 63);
            const int slot = (int)(rlo & 0x1FFFu);
            float2 wxy = xy[slot];
            float2 wzd = zd[slot];
            cx = wxy.x; cy = wxy.y; cz = wzd.x;
            // bank the center into the wave-0 LDS ring (slot = it mod PUB)
            if (t == 0) {
                const int rs = (it & (PUB - 1)) * 3;
                cbuf[rs] = cx; cbuf[rs + 1] = cy; cbuf[rs + 2] = cz;
            }
            // every PUB iters: lanes 0-47 of WAVE 0 flush PUB centers with
            // relaxed agent-scope stores (same-wave DS ordering covers the
            // slot written this iteration), then one relaxed prog store.
            if ((it & (PUB - 1)) == (PUB - 1)) {
                if (t < 3 * PUB) {
                    const int base3 = (it & ~(PUB - 1)) * 3;
                    __hip_atomic_store(&nxz_i[base3 + t],
                                       __float_as_int(cbuf[t]),
                                       __ATOMIC_RELAXED,
                                       __HIP_MEMORY_SCOPE_AGENT);
                }
                if (t == 0) {
                    __hip_atomic_store(&prog[b], it + 1, __ATOMIC_RELAXED,
                                       __HIP_MEMORY_SCOPE_AGENT);
                }
            }
        }
        return;
    }

    // ======================= worker path ===================================
    float (*g)[NCH][NSAMPLE] = (float (*)[NCH][NSAMPLE])smem;  // 68608 B
    int (*idx)[NSAMPLE] = (int (*)[NSAMPLE])(smem + 68608);    //  1024 B
    float (*cc)[4] = (float (*)[4])(smem + 69632);             //   128 B
    int* tk_s = (int*)(smem + 69760);

    const int* nxz_all = (const int*)new_xyz;

    for (;;) {
        if (t == 0) *tk_s = atomicAdd(ticket, 1);
        __syncthreads();
        const int T = *tk_s;
        __syncthreads();
        if (T >= NTICK) break;
        const int b   = T & 3;
        const int it0 = (T >> 2) * TPT;

        const float* pts = points + (size_t)b * NPTS * 3;
        const float* fts = features + (size_t)b * NPTS * 64;
        const int gci = b * NPOINT + it0 + w;   // this wave's center

        // ---- level 1: block-level poll of prog[b] (single hot line) -------
        if (t == 0) {
            while (__hip_atomic_load(&prog[b], __ATOMIC_RELAXED,
                                     __HIP_MEMORY_SCOPE_AGENT) < it0 + TPT)
                __builtin_amdgcn_s_sleep(32);
        }
        __syncthreads();

        // ---- level 2: per-center sentinel backstop (data-as-flag) ---------
        float cxw = 0.f, cyw = 0.f, czw = 0.f;
        if (lane == 0) {
            unsigned v;
            do {
                v = (unsigned)__hip_atomic_load(&nxz_all[3 * gci + 0],
                        __ATOMIC_RELAXED, __HIP_MEMORY_SCOPE_AGENT);
                if (v != SENT) break;
                __builtin_amdgcn_s_sleep(2);
            } while (true);
            cxw = __uint_as_float(v);
            do {
                v = (unsigned)__hip_atomic_load(&nxz_all[3 * gci + 1],
                        __ATOMIC_RELAXED, __HIP_MEMORY_SCOPE_AGENT);
                if (v != SENT) break;
                __builtin_amdgcn_s_sleep(2);
            } while (true);
            cyw = __uint_as_float(v);
            do {
                v = (unsigned)__hip_atomic_load(&nxz_all[3 * gci + 2],
                        __ATOMIC_RELAXED, __HIP_MEMORY_SCOPE_AGENT);
                if (v != SENT) break;
                __builtin_amdgcn_s_sleep(2);
            } while (true);
            czw = __uint_as_float(v);
        }
        cxw = __shfl(cxw, 0); cyw = __shfl(cyw, 0); czw = __shfl(czw, 0);
        if (lane == 0) { cc[w][0] = cxw; cc[w][1] = cyw; cc[w][2] = czw; }

        // ---- ball query: wave w handles center it0+w (bit-exact) ----------
        {
#pragma clang fp contract(off)
            const float r2 = (float)(0.2 * 0.2);
            int* out = idx[w];
            int cnt = 0, first = 0;
            bool havefirst = false;
            for (int base = 0; base < NPTS && cnt < NSAMPLE; base += 64) {
                const int j = base + lane;
                float dx = pts[3 * j + 0] - cxw;
                float dy = pts[3 * j + 1] - cyw;
                float dz = pts[3 * j + 2] - czw;
                float d2 = ((dx * dx) + (dy * dy)) + (dz * dz);
                const bool in = d2 < r2;
                unsigned long long m = __ballot(in);
                if (in) {
                    int pos = cnt + __popcll(m & ((1ull << lane) - 1ull));
                    if (pos < NSAMPLE) out[pos] = j;
                }
                if (!havefirst && m != 0ull) {
                    first = base + (__ffsll((long long)m) - 1);
                    havefirst = true;
                }
                cnt += __popcll(m);
            }
            if (lane >= cnt && lane < NSAMPLE) out[lane] = first;
        }
        __syncthreads();

        // ---- gather: 256 slots, slot = p*32+s ----
        if (t < TPT * NSAMPLE) {
            const int p = t >> 5;
            const int s = t & 31;
            const int j = idx[p][s];
            const float* pj = pts + 3 * j;
            g[p][0][s] = pj[0] - cc[p][0];
            g[p][1][s] = pj[1] - cc[p][1];
            g[p][2][s] = pj[2] - cc[p][2];
            const float4* fj = (const float4*)(fts + (size_t)j * 64);
#pragma unroll
            for (int c4 = 0; c4 < 16; ++c4) {
                float4 v = fj[c4];
                g[p][3 + 4 * c4 + 0][s] = v.x;
                g[p][3 + 4 * c4 + 1][s] = v.y;
                g[p][3 + 4 * c4 + 2][s] = v.z;
                g[p][3 + 4 * c4 + 3][s] = v.w;
            }
        }
        __syncthreads();

        // ---- conv: o = t&127, quad q = t>>7 handles centers q and q+4 ----
        {
            const int o = t & 127;
            const int q = t >> 7;
            float acc0 = 0.f, acc1 = 0.f;
            const float* wr = weight + (size_t)o * NCH * NSAMPLE;
            for (int c = 0; c < NCH; ++c) {
                const float4* w4 = (const float4*)(wr + c * NSAMPLE);
#pragma unroll
                for (int s4 = 0; s4 < 8; ++s4) {
                    float4 wv = w4[s4];
                    float4 g0 = *(const float4*)&g[q][c][s4 * 4];
                    float4 g1 = *(const float4*)&g[q + 4][c][s4 * 4];
                    acc0 += g0.x * wv.x + g0.y * wv.y + g0.z * wv.z + g0.w * wv.w;
                    acc1 += g1.x * wv.x + g1.y * wv.y + g1.z * wv.z + g1.w * wv.w;
                }
            }
            float* outp = conv_out + ((size_t)b * NPOINT + it0) * NOUT;
            outp[(q    ) * NOUT + o] = acc0;
            outp[(q + 4) * NOUT + o] = acc1;
        }
        __syncthreads();   // protect g/idx/cc before next ticket's writes
    }
}

extern "C" void kernel_launch(void* const* d_in, const int* in_sizes, int n_in,
                              void* d_out, int out_size, void* d_ws, size_t ws_size,
                              hipStream_t stream)
{
    const float* points   = (const float*)d_in[0];
    const float* features = (const float*)d_in[1];
    const float* weight   = (const float*)d_in[2];

    float* new_xyz = (float*)d_out;                              // (4,2048,3)
    float* conv    = (float*)d_out + (size_t)BATCH * NPOINT * 3; // (4,2048,128)
    int* ctl = (int*)d_ws;   // prog[4] @0, ticket @ +128B

    hipMemsetAsync(d_ws, 0, 256, stream);
    // seed new_xyz with 0xFFFFFFFF sentinel (NaN bits): data doubles as flag
    hipMemsetAsync(new_xyz, 0xFF, (size_t)BATCH * NPOINT * 3 * 4, stream);
    fused_kernel<<<NBLK, FPS_T, 0, stream>>>(points, features, weight,
                                             new_xyz, conv, ctl);
}